// Round 16
// baseline (597.631 us; speedup 1.0000x reference)
//
#include <hip/hip_runtime.h>
#include <hip/hip_bf16.h>

#define EPS_F 1e-10f

typedef short s16x8 __attribute__((ext_vector_type(8)));
typedef float f32x4 __attribute__((ext_vector_type(4)));
typedef unsigned short ushort_t;

constexpr int B_ = 8, S_ = 4, C_ = 512, Cq_ = 128, HW_ = 4096;

__device__ inline float bf_lo(unsigned int u) { return __uint_as_float(u << 16); }
__device__ inline float bf_hi(unsigned int u) { return __uint_as_float(u & 0xffff0000u); }

__device__ inline ushort_t f2bf(float f) {
    __hip_bfloat16 h = __float2bfloat16(f);
    return *reinterpret_cast<ushort_t*>(&h);
}
__device__ inline unsigned int pack_bf2(float a, float b) {
    return (unsigned int)f2bf(a) | ((unsigned int)f2bf(b) << 16);
}
__device__ inline float dot2u(unsigned int a, unsigned int b) {
    return bf_lo(a) * bf_lo(b) + bf_hi(a) * bf_hi(b);
}

#define GLOAD16(gp, lp) __builtin_amdgcn_global_load_lds( \
    (const __attribute__((address_space(1))) unsigned int*)(gp), \
    (__attribute__((address_space(3))) unsigned int*)(lp), 16, 0, 0)

#define VMCNT0 asm volatile("s_waitcnt vmcnt(0)" ::: "memory")
#define LGK0   asm volatile("s_waitcnt lgkmcnt(0)" ::: "memory")
#define MFMA16(a, b, c) __builtin_amdgcn_mfma_f32_16x16x32_bf16(a, b, c, 0, 0, 0)

// swizzle involution over 8 chunk slots
#define SWZ(p) ((((p) >> 3) & 7) ^ ((p) & 7))

// ---------------------------------------------------------------------------
// prepQ: fp32->bf16 Q/K weights only, pre-swizzled (slot = c ^ (row&7)).
// (Wv is now blended per (b,s) by wprep13 after attention.)
// ---------------------------------------------------------------------------
__global__ __launch_bounds__(256) void prepQ(
    const float* __restrict__ wq, const float* __restrict__ wk,
    ushort_t* __restrict__ Wqk_pre) {
    int gid = blockIdx.x * 256 + threadIdx.x;    // < 65536
    int s = gid >> 14;
    int kt = (gid >> 11) & 7;
    int row = (gid >> 3) & 255;
    int slot = gid & 7;
    int col = kt * 64 + ((slot ^ (row & 7)) << 3);
    const float* src = (row < 128)
        ? &wq[((size_t)s * 128 + row) * 512 + col]
        : &wk[((size_t)s * 128 + (row - 128)) * 512 + col];
    float4 f0 = *reinterpret_cast<const float4*>(src);
    float4 f1 = *reinterpret_cast<const float4*>(src + 4);
    uint4 o;
    o.x = pack_bf2(f0.x, f0.y); o.y = pack_bf2(f0.z, f0.w);
    o.z = pack_bf2(f1.x, f1.y); o.w = pack_bf2(f1.z, f1.w);
    *reinterpret_cast<uint4*>(Wqk_pre + (size_t)gid * 8) = o;
}

// ===========================================================================
// qkg (r12, unchanged): FUSED projections + Gram partials + xbfT emission.
// xbfT layout: element (bt*HW + p)*512 + c  (channel-linear per pixel).
// ===========================================================================
__global__ __launch_bounds__(512, 4) void qkg(
    const ushort_t* __restrict__ Wqk_pre, const float* __restrict__ x,
    const float* __restrict__ bq, const float* __restrict__ bk,
    ushort_t* __restrict__ xbfT, float* __restrict__ g4) {

    const int b = blockIdx.x & 7;
    const int pblk = blockIdx.x >> 3;
    const int p0 = pblk * 32;

    __shared__ __align__(16) ushort_t As[2][16384];   // 64KB
    __shared__ __align__(16) ushort_t Bs[2][2048];    // 8KB

    const int tid = threadIdx.x;
    const int w = tid >> 6, lane = tid & 63;
    const int w4 = w * 4;
    const int li = lane & 15, lk = lane >> 4;
    const int aq_row = 16 * w + li;
    const int ak_row = 128 + 16 * w + li;
    const int ob4 = 16 * w + lk * 4;

    int a_sl[2], b_sl0[2], b_sl1[2];
#pragma unroll
    for (int h = 0; h < 2; ++h) {
        a_sl[h]  = (((h * 4 + lk) ^ (li & 7)) << 3);
        b_sl0[h] = (((h * 4 + lk) ^ SWZ(li)) << 3);
        b_sl1[h] = (((h * 4 + lk) ^ SWZ(16 + li)) << 3);
    }

    const int sk = tid >> 3, spb = (tid & 7) * 4;
    const int ep = tid >> 3, esl = tid & 7;
    const int ec = esl ^ SWZ(ep);

    f32x4 accq[2], acck[2];
#pragma unroll
    for (int i = 0; i < 2; ++i) { accq[i] = 0.f; acck[i] = 0.f; }
    unsigned int Qr[4][4], Kr[4][4];
    float4 nb;

#define STAGE_AG(TS, BUF)                                                    \
    { const ushort_t* _tp = Wqk_pre +                                        \
          ((size_t)(((TS) >> 3) * 8 + ((TS) & 7)) << 14);                    \
      ushort_t* _ld = &As[BUF][0];                                           \
      _Pragma("unroll")                                                      \
      for (int _i = 0; _i < 4; ++_i)                                         \
          GLOAD16(_tp + ((w4 + _i) << 9) + (lane << 3),                      \
                  _ld + ((w4 + _i) << 9)); }

#define LOAD_BG(TS)                                                          \
    nb = *reinterpret_cast<const float4*>(                                   \
        x + ((size_t)(b * 4 + ((TS) >> 3)) * C_ + ((TS) & 7) * 64 + sk) * HW_\
        + p0 + spb)

#define WRITE_BG(BUF)                                                        \
    { float _vv[4] = {nb.x, nb.y, nb.z, nb.w};                               \
      _Pragma("unroll")                                                      \
      for (int _j = 0; _j < 4; ++_j) {                                       \
          int _p = spb + _j;                                                 \
          Bs[BUF][_p * 64 + (((sk >> 3) ^ SWZ(_p)) << 3) + (sk & 7)]         \
              = f2bf(_vv[_j]);                                               \
      } }

#define EMITG(TS, BUF)                                                       \
    if (w < 4) {                                                             \
        s16x8 _ev = *reinterpret_cast<const s16x8*>(&Bs[BUF][tid * 8]);      \
        *reinterpret_cast<s16x8*>(                                           \
            xbfT + ((size_t)(b * 4 + ((TS) >> 3)) * HW_ + p0 + ep) * 512     \
            + ((TS) & 7) * 64 + ec * 8) = _ev;                               \
    }

#define COMPUTEG(BUF)                                                        \
    { _Pragma("unroll")                                                      \
      for (int h = 0; h < 2; ++h) {                                          \
          s16x8 aq = *reinterpret_cast<const s16x8*>(                        \
              &As[BUF][aq_row * 64 + a_sl[h]]);                              \
          s16x8 ak = *reinterpret_cast<const s16x8*>(                        \
              &As[BUF][ak_row * 64 + a_sl[h]]);                              \
          s16x8 b0 = *reinterpret_cast<const s16x8*>(                        \
              &Bs[BUF][li * 64 + b_sl0[h]]);                                 \
          s16x8 b1 = *reinterpret_cast<const s16x8*>(                        \
              &Bs[BUF][(16 + li) * 64 + b_sl1[h]]);                          \
          __builtin_amdgcn_s_setprio(1);                                     \
          accq[0] = MFMA16(aq, b0, accq[0]);                                 \
          accq[1] = MFMA16(aq, b1, accq[1]);                                 \
          acck[0] = MFMA16(ak, b0, acck[0]);                                 \
          acck[1] = MFMA16(ak, b1, acck[1]);                                 \
          __builtin_amdgcn_s_setprio(0);                                     \
      } }

#define PACKG(T)                                                             \
    {   float4 _bqv = *reinterpret_cast<const float4*>(bq + (T) * 128 + ob4);\
        float4 _bkv = *reinterpret_cast<const float4*>(bk + (T) * 128 + ob4);\
        _Pragma("unroll")                                                    \
        for (int _ph = 0; _ph < 2; ++_ph) {                                  \
            Qr[T][_ph * 2 + 0] = pack_bf2(accq[_ph][0] + _bqv.x,             \
                                          accq[_ph][1] + _bqv.y);            \
            Qr[T][_ph * 2 + 1] = pack_bf2(accq[_ph][2] + _bqv.z,             \
                                          accq[_ph][3] + _bqv.w);            \
            Kr[T][_ph * 2 + 0] = pack_bf2(acck[_ph][0] + _bkv.x,             \
                                          acck[_ph][1] + _bkv.y);            \
            Kr[T][_ph * 2 + 1] = pack_bf2(acck[_ph][2] + _bkv.z,             \
                                          acck[_ph][3] + _bkv.w);            \
            accq[_ph] = 0.f;                                                 \
            acck[_ph] = 0.f;                                                 \
        } }

    LOAD_BG(0);
    STAGE_AG(0, 0);
    WRITE_BG(0);
    VMCNT0; LGK0;
    __builtin_amdgcn_s_barrier();

#pragma unroll
    for (int ts = 0; ts < 32; ++ts) {
        if (ts < 31) { LOAD_BG(ts + 1); STAGE_AG(ts + 1, (ts + 1) & 1); }
        EMITG(ts, ts & 1);
        COMPUTEG(ts & 1);
        if (ts == 7)  PACKG(0);
        if (ts == 15) PACKG(1);
        if (ts == 23) PACKG(2);
        if (ts == 31) PACKG(3);
        if (ts < 31) {
            WRITE_BG((ts + 1) & 1);
            VMCNT0; LGK0;
            __builtin_amdgcn_s_barrier();
        }
    }

#undef STAGE_AG
#undef LOAD_BG
#undef WRITE_BG
#undef EMITG
#undef COMPUTEG
#undef PACKG

    float d[24];
#pragma unroll
    for (int t1 = 0; t1 < 4; ++t1)
#pragma unroll
        for (int t2 = 0; t2 < 4; ++t2) {
            float s = 0.f;
#pragma unroll
            for (int j = 0; j < 4; ++j) s += dot2u(Qr[t1][j], Kr[t2][j]);
            d[t1 * 4 + t2] = s;
        }
#pragma unroll
    for (int t = 0; t < 4; ++t) {
        float sq = 0.f, sk2 = 0.f;
#pragma unroll
        for (int j = 0; j < 4; ++j) {
            sq += dot2u(Qr[t][j], Qr[t][j]);
            sk2 += dot2u(Kr[t][j], Kr[t][j]);
        }
        d[16 + t] = sq;
        d[20 + t] = sk2;
    }

    __shared__ float red[8][24];
#pragma unroll
    for (int e = 0; e < 24; ++e) {
        float v = d[e];
#pragma unroll
        for (int o = 32; o > 0; o >>= 1) v += __shfl_down(v, o);
        if (lane == 0) red[w][e] = v;
    }
    __syncthreads();
    if (tid < 24) {
        float t = 0.f;
#pragma unroll
        for (int ww = 0; ww < 8; ++ww) t += red[ww][tid];
        g4[((size_t)b * 24 + tid) * 128 + pblk] = t;
    }
}

// ---------------------------------------------------------------------------
// att_k6: sum 128 gram chunks, cosine energy + softmax -> att (B,S,S)
// ---------------------------------------------------------------------------
__global__ void att_k6(const float* __restrict__ g4, float* __restrict__ att) {
    __shared__ float sm[8][24];
    const int tid = threadIdx.x;
    if (tid < 192) {
        const int b = tid / 24, e = tid % 24;
        const float* p = g4 + ((size_t)b * 24 + e) * 128;
        float t = 0.f;
        for (int ch = 0; ch < 128; ++ch) t += p[ch];
        sm[b][e] = t;
    }
    __syncthreads();
    if (tid < 8) {
        const int b = tid;
        float nq[4], nk[4];
#pragma unroll
        for (int s = 0; s < 4; ++s) {
            nq[s] = sqrtf(sm[b][16 + s]) + EPS_F;
            nk[s] = sqrtf(sm[b][20 + s]) + EPS_F;
        }
#pragma unroll
        for (int s = 0; s < 4; ++s) {
            float e[4], m = -1e30f;
#pragma unroll
            for (int t = 0; t < 4; ++t) {
                e[t] = sm[b][s * 4 + t] / (nq[s] * nk[t]);
                m = fmaxf(m, e[t]);
            }
            float sum = 0.f;
#pragma unroll
            for (int t = 0; t < 4; ++t) { e[t] = expf(e[t] - m); sum += e[t]; }
#pragma unroll
            for (int t = 0; t < 4; ++t)
                att[(size_t)(b * 4 + s) * 4 + t] = e[t] / sum;
        }
    }
}

// ===========================================================================
// wprep13: blended V-weights, pre-swizzled bf16.
//   Wcat[b,s] = [att[s,0]*Wv[0] | ... | att[s,3]*Wv[3]]  (512 x 2048)
// Layout: Wcat_pre[bs][ctile(4)][ts(32)][row(128)][slot(8)][8],
//   slot = kchunk ^ (row&7), global k = ts*64 + chunk*8, t = k>>9, kc = k&511.
// ===========================================================================
__global__ __launch_bounds__(256) void wprep13(
    const float* __restrict__ wv, const float* __restrict__ att,
    ushort_t* __restrict__ Wcat_pre) {
    int gid = blockIdx.x * 256 + threadIdx.x;   // < 4,194,304
    int slot  = gid & 7;
    int row   = (gid >> 3) & 127;
    int ts    = (gid >> 10) & 31;
    int ctile = (gid >> 15) & 3;
    int bs    = gid >> 17;                       // 0..31
    int k  = ts * 64 + ((slot ^ (row & 7)) << 3);
    int t  = k >> 9, kc = k & 511;
    int c  = ctile * 128 + row;
    float a = att[(size_t)bs * 4 + t];
    const float* src = wv + ((size_t)t * 512 + c) * 512 + kc;
    float4 f0 = *reinterpret_cast<const float4*>(src);
    float4 f1 = *reinterpret_cast<const float4*>(src + 4);
    uint4 o;
    o.x = pack_bf2(a * f0.x, a * f0.y); o.y = pack_bf2(a * f0.z, a * f0.w);
    o.z = pack_bf2(a * f1.x, a * f1.y); o.w = pack_bf2(a * f1.z, a * f1.w);
    *reinterpret_cast<uint4*>(Wcat_pre + (size_t)gid * 8) = o;
}

// ===========================================================================
// vgemm13: PURE batched GEMM  out[b,s] = Wcat[b,s](512x2048) @ Xstack(2048xHW)
// + bias-blend + residual. No in-loop blend, no mst: acc[4][2] = 32 regs.
// Block 128c x 64p, 256 thr = 4 waves (2x2), wave 64c x 32p, BK=64, 32 steps.
// 16 MFMA : 12 ds_read : 6 gload per wave-step (2x the density of vblend).
// LDS 48KB -> 3 blocks/CU. ctile innermost (L2 B-sharing); b pinned to XCD.
// ===========================================================================
__global__ __launch_bounds__(256, 4) void vgemm13(
    const ushort_t* __restrict__ Wcat_pre, const ushort_t* __restrict__ xbfT,
    const float* __restrict__ bv, const float* __restrict__ att,
    const float* __restrict__ gamma, float* __restrict__ out) {

    // 8192 blocks: b = blk&7; idx: s(4) x ptile(64) x ctile(4), ctile inner
    const int b = blockIdx.x & 7;
    const int idx = blockIdx.x >> 3;         // 0..1023
    const int ctile = idx & 3;
    const int ptile = (idx >> 2) & 63;
    const int s = idx >> 8;
    const int p0 = ptile * 64;
    const int c0 = ctile * 128;

    __shared__ __align__(16) ushort_t AsAll[2 * 8192];   // 32KB
    __shared__ __align__(16) ushort_t BsAll[2 * 4096];   // 16KB

    const int tid = threadIdx.x;
    const int w = tid >> 6, lane = tid & 63;
    const int wr2 = w >> 1, wc2 = w & 1;
    const int li = lane & 15, lk = lane >> 4;

    int a_sl[2], b_sl[2], b_sl1[2];
    const int bp = wc2 * 32 + li;
    const int bp1 = bp + 16;
#pragma unroll
    for (int h = 0; h < 2; ++h) {
        a_sl[h] = (((h * 4 + lk) ^ (li & 7)) << 3);
        b_sl[h] = (((h * 4 + lk) ^ SWZ(bp)) << 3);
        b_sl1[h] = (((h * 4 + lk) ^ SWZ(bp1)) << 3);
    }

    // B staging: 512 chunks, 2/thread (chunk = i*256+tid)
    int bst_p[2], bst_c[2];
#pragma unroll
    for (int i = 0; i < 2; ++i) {
        int ch = i * 256 + tid;
        bst_p[i] = ch >> 3;
        bst_c[i] = (ch & 7) ^ SWZ(bst_p[i]);
    }

    f32x4 acc[4][2];
#pragma unroll
    for (int mf = 0; mf < 4; ++mf)
#pragma unroll
        for (int nf = 0; nf < 2; ++nf) acc[mf][nf] = 0.f;

#define STAGE13(TS, BUF)                                                     \
    {   const int _t = (TS) >> 3, _kt = (TS) & 7;                            \
        const ushort_t* _ap = Wcat_pre +                                     \
            ((((size_t)(b * 4 + s) * 4 + ctile) * 32 + (TS)) << 13);         \
        ushort_t* _al = &AsAll[(BUF) * 8192];                                \
        _Pragma("unroll")                                                    \
        for (int _i = 0; _i < 4; ++_i)                                       \
            GLOAD16(_ap + ((_i * 256 + tid) << 3),                           \
                    _al + ((_i * 256 + tid) << 3));                          \
        const ushort_t* _bb = xbfT + (size_t)(b * 4 + _t) * HW_ * 512;       \
        _Pragma("unroll")                                                    \
        for (int _i = 0; _i < 2; ++_i)                                       \
            GLOAD16(_bb + ((size_t)(p0 + bst_p[_i])) * 512 + _kt * 64        \
                        + bst_c[_i] * 8,                                     \
                    &BsAll[(BUF) * 4096 + ((_i * 256 + tid) << 3)]);         \
    }

#define COMPUTE13(BUF)                                                      \
    {   const int _ab = (BUF) * 8192, _bbf = (BUF) * 4096;                  \
        _Pragma("unroll")                                                    \
        for (int h = 0; h < 2; ++h) {                                        \
            s16x8 af0 = *reinterpret_cast<const s16x8*>(                     \
                &AsAll[_ab + (wr2 * 64 + 0 * 16 + li) * 64 + a_sl[h]]);      \
            s16x8 af1 = *reinterpret_cast<const s16x8*>(                     \
                &AsAll[_ab + (wr2 * 64 + 1 * 16 + li) * 64 + a_sl[h]]);      \
            s16x8 af2 = *reinterpret_cast<const s16x8*>(                     \
                &AsAll[_ab + (wr2 * 64 + 2 * 16 + li) * 64 + a_sl[h]]);      \
            s16x8 af3 = *reinterpret_cast<const s16x8*>(                     \
                &AsAll[_ab + (wr2 * 64 + 3 * 16 + li) * 64 + a_sl[h]]);      \
            s16x8 bf0 = *reinterpret_cast<const s16x8*>(                     \
                &BsAll[_bbf + bp * 64 + b_sl[h]]);                           \
            s16x8 bf1 = *reinterpret_cast<const s16x8*>(                     \
                &BsAll[_bbf + bp1 * 64 + b_sl1[h]]);                         \
            __builtin_amdgcn_s_setprio(1);                                   \
            acc[0][0] = MFMA16(af0, bf0, acc[0][0]);                         \
            acc[0][1] = MFMA16(af0, bf1, acc[0][1]);                         \
            acc[1][0] = MFMA16(af1, bf0, acc[1][0]);                         \
            acc[1][1] = MFMA16(af1, bf1, acc[1][1]);                         \
            acc[2][0] = MFMA16(af2, bf0, acc[2][0]);                         \
            acc[2][1] = MFMA16(af2, bf1, acc[2][1]);                         \
            acc[3][0] = MFMA16(af3, bf0, acc[3][0]);                         \
            acc[3][1] = MFMA16(af3, bf1, acc[3][1]);                         \
            __builtin_amdgcn_s_setprio(0);                                   \
        } }

    STAGE13(0, 0);
    VMCNT0;
    __builtin_amdgcn_s_barrier();

#pragma unroll
    for (int ts = 0; ts < 32; ++ts) {
        if (ts < 31) STAGE13(ts + 1, (ts + 1) & 1);
        COMPUTE13(ts & 1);
        if (ts < 31) {
            VMCNT0;
            __builtin_amdgcn_s_barrier();
        }
    }

#undef STAGE13
#undef COMPUTE13

    // epilogue: out = gm*(acc + sum_t att*bv) + bf16_residual (from xbfT)
    const float gm = gamma[0];
    float attv[4];
#pragma unroll
    for (int t = 0; t < 4; ++t)
        attv[t] = __uint_as_float(__builtin_amdgcn_readfirstlane(
            __float_as_uint(att[(size_t)(b * 4 + s) * 4 + t])));

    const int cbase = c0 + wr2 * 64 + lk * 4;
    float bsv[4][4];   // [mf][r]
#pragma unroll
    for (int mf = 0; mf < 4; ++mf)
#pragma unroll
        for (int r = 0; r < 4; ++r) {
            int c = cbase + mf * 16 + r;
            bsv[mf][r] = attv[0] * bv[0 * 512 + c] + attv[1] * bv[1 * 512 + c]
                       + attv[2] * bv[2 * 512 + c] + attv[3] * bv[3 * 512 + c];
        }

#pragma unroll
    for (int nf = 0; nf < 2; ++nf) {
        const int p = p0 + wc2 * 32 + nf * 16 + li;
        const ushort_t* rb =
            xbfT + ((size_t)(b * 4 + s) * HW_ + p) * 512 + cbase;
#pragma unroll
        for (int mf = 0; mf < 4; ++mf) {
            const uint2 v = *reinterpret_cast<const uint2*>(rb + mf * 16);
#pragma unroll
            for (int r = 0; r < 4; ++r) {
                float resid = (r == 0) ? bf_lo(v.x)
                            : (r == 1) ? bf_hi(v.x)
                            : (r == 2) ? bf_lo(v.y)
                                       : bf_hi(v.y);
                int c = cbase + mf * 16 + r;
                size_t off = ((size_t)(b * 4 + s) * C_ + c) * HW_ + p;
                out[off] = gm * (acc[mf][nf][r] + bsv[mf][r]) + resid;
            }
        }
    }
}

extern "C" void kernel_launch(void* const* d_in, const int* in_sizes, int n_in,
                              void* d_out, int out_size, void* d_ws, size_t ws_size,
                              hipStream_t stream) {
    const float* x     = (const float*)d_in[0];
    const float* wq    = (const float*)d_in[1];
    const float* bq    = (const float*)d_in[2];
    const float* wk    = (const float*)d_in[3];
    const float* bk    = (const float*)d_in[4];
    const float* wv    = (const float*)d_in[5];
    const float* bv    = (const float*)d_in[6];
    const float* gamma = (const float*)d_in[7];
    float* out = (float*)d_out;

    // ws: 1.05 + 0.10 + 134.22 + 67.11 MB = 202.5 MB (< 206.6 proven in r5)
    char* ws = (char*)d_ws;
    ushort_t* Wqk_pre  = (ushort_t*)ws;                          // 1.05 MB
    float*    g4       = (float*)(Wqk_pre + (size_t)4 * 8 * 256 * 64);
    float*    att      = g4 + (size_t)8 * 24 * 128;
    ushort_t* xbfT     = (ushort_t*)(att + 128);                 // 134.2 MB
    ushort_t* Wcat_pre = xbfT + (size_t)32 * HW_ * 512;          // 67.1 MB

    prepQ<<<256, 256, 0, stream>>>(wq, wk, Wqk_pre);
    qkg<<<1024, 512, 0, stream>>>(Wqk_pre, x, bq, bk, xbfT, g4);
    att_k6<<<1, 256, 0, stream>>>(g4, att);
    wprep13<<<16384, 256, 0, stream>>>(wv, att, Wcat_pre);
    vgemm13<<<8192, 256, 0, stream>>>(Wcat_pre, xbfT, bv, att, gamma, out);
}

// Round 17
// 394.178 us; speedup vs baseline: 1.5161x; 1.5161x over previous
//
#include <hip/hip_runtime.h>
#include <hip/hip_bf16.h>

#define EPS_F 1e-10f

typedef short s16x8 __attribute__((ext_vector_type(8)));
typedef float f32x4 __attribute__((ext_vector_type(4)));
typedef unsigned short ushort_t;

constexpr int B_ = 8, S_ = 4, C_ = 512, Cq_ = 128, HW_ = 4096;

__device__ inline float bf_lo(unsigned int u) { return __uint_as_float(u << 16); }
__device__ inline float bf_hi(unsigned int u) { return __uint_as_float(u & 0xffff0000u); }

__device__ inline ushort_t f2bf(float f) {
    __hip_bfloat16 h = __float2bfloat16(f);
    return *reinterpret_cast<ushort_t*>(&h);
}
__device__ inline unsigned int pack_bf2(float a, float b) {
    return (unsigned int)f2bf(a) | ((unsigned int)f2bf(b) << 16);
}
__device__ inline float dot2u(unsigned int a, unsigned int b) {
    return bf_lo(a) * bf_lo(b) + bf_hi(a) * bf_hi(b);
}

#define GLOAD16(gp, lp) __builtin_amdgcn_global_load_lds( \
    (const __attribute__((address_space(1))) unsigned int*)(gp), \
    (__attribute__((address_space(3))) unsigned int*)(lp), 16, 0, 0)

#define VMCNT0 asm volatile("s_waitcnt vmcnt(0)" ::: "memory")
#define LGK0   asm volatile("s_waitcnt lgkmcnt(0)" ::: "memory")
#define MFMA16(a, b, c) __builtin_amdgcn_mfma_f32_16x16x32_bf16(a, b, c, 0, 0, 0)

// swizzle involution over 8 chunk slots
#define SWZ(p) ((((p) >> 3) & 7) ^ ((p) & 7))

// ---------------------------------------------------------------------------
// prep3: fp32->bf16 weights, pre-swizzled (chunk slot = c ^ (row&7)).
// ---------------------------------------------------------------------------
__global__ __launch_bounds__(256) void prep3(
    const float* __restrict__ wq, const float* __restrict__ wk,
    const float* __restrict__ wv,
    ushort_t* __restrict__ Wqk_pre, ushort_t* __restrict__ Wvb_pre) {
    int gid = blockIdx.x * 256 + threadIdx.x;
    if (gid < 65536) {                      // Wqk chunks
        int s = gid >> 14;
        int kt = (gid >> 11) & 7;
        int row = (gid >> 3) & 255;
        int slot = gid & 7;
        int col = kt * 64 + ((slot ^ (row & 7)) << 3);
        const float* src = (row < 128)
            ? &wq[((size_t)s * 128 + row) * 512 + col]
            : &wk[((size_t)s * 128 + (row - 128)) * 512 + col];
        float4 f0 = *reinterpret_cast<const float4*>(src);
        float4 f1 = *reinterpret_cast<const float4*>(src + 4);
        uint4 o;
        o.x = pack_bf2(f0.x, f0.y); o.y = pack_bf2(f0.z, f0.w);
        o.z = pack_bf2(f1.x, f1.y); o.w = pack_bf2(f1.z, f1.w);
        *reinterpret_cast<uint4*>(Wqk_pre + (size_t)gid * 8) = o;
    } else {                                 // Wvb chunks
        int c2 = gid - 65536;                // < 131072
        int t = c2 >> 15;
        int ct = (c2 >> 14) & 1;
        int kt = (c2 >> 11) & 7;
        int row = (c2 >> 3) & 255;
        int slot = c2 & 7;
        int col = kt * 64 + ((slot ^ (row & 7)) << 3);
        const float* src = &wv[((size_t)t * 512 + ct * 256 + row) * 512 + col];
        float4 f0 = *reinterpret_cast<const float4*>(src);
        float4 f1 = *reinterpret_cast<const float4*>(src + 4);
        uint4 o;
        o.x = pack_bf2(f0.x, f0.y); o.y = pack_bf2(f0.z, f0.w);
        o.z = pack_bf2(f1.x, f1.y); o.w = pack_bf2(f1.z, f1.w);
        *reinterpret_cast<uint4*>(Wvb_pre + (size_t)c2 * 8) = o;
    }
}

// ===========================================================================
// qkg: FUSED projections + Gram partials + xbfT emission.
// xbfT layout: element (bt*HW + p)*512 + c  (channel-linear per pixel).
// ===========================================================================
__global__ __launch_bounds__(512, 4) void qkg(
    const ushort_t* __restrict__ Wqk_pre, const float* __restrict__ x,
    const float* __restrict__ bq, const float* __restrict__ bk,
    ushort_t* __restrict__ xbfT, float* __restrict__ g4) {

    const int b = blockIdx.x & 7;
    const int pblk = blockIdx.x >> 3;
    const int p0 = pblk * 32;

    __shared__ __align__(16) ushort_t As[2][16384];   // 64KB
    __shared__ __align__(16) ushort_t Bs[2][2048];    // 8KB

    const int tid = threadIdx.x;
    const int w = tid >> 6, lane = tid & 63;
    const int w4 = w * 4;
    const int li = lane & 15, lk = lane >> 4;
    const int aq_row = 16 * w + li;
    const int ak_row = 128 + 16 * w + li;
    const int ob4 = 16 * w + lk * 4;

    int a_sl[2], b_sl0[2], b_sl1[2];
#pragma unroll
    for (int h = 0; h < 2; ++h) {
        a_sl[h]  = (((h * 4 + lk) ^ (li & 7)) << 3);
        b_sl0[h] = (((h * 4 + lk) ^ SWZ(li)) << 3);
        b_sl1[h] = (((h * 4 + lk) ^ SWZ(16 + li)) << 3);
    }

    const int sk = tid >> 3, spb = (tid & 7) * 4;
    const int ep = tid >> 3, esl = tid & 7;
    const int ec = esl ^ SWZ(ep);

    f32x4 accq[2], acck[2];
#pragma unroll
    for (int i = 0; i < 2; ++i) { accq[i] = 0.f; acck[i] = 0.f; }
    unsigned int Qr[4][4], Kr[4][4];
    float4 nb;

#define STAGE_AG(TS, BUF)                                                    \
    { const ushort_t* _tp = Wqk_pre +                                        \
          ((size_t)(((TS) >> 3) * 8 + ((TS) & 7)) << 14);                    \
      ushort_t* _ld = &As[BUF][0];                                           \
      _Pragma("unroll")                                                      \
      for (int _i = 0; _i < 4; ++_i)                                         \
          GLOAD16(_tp + ((w4 + _i) << 9) + (lane << 3),                      \
                  _ld + ((w4 + _i) << 9)); }

#define LOAD_BG(TS)                                                          \
    nb = *reinterpret_cast<const float4*>(                                   \
        x + ((size_t)(b * 4 + ((TS) >> 3)) * C_ + ((TS) & 7) * 64 + sk) * HW_\
        + p0 + spb)

#define WRITE_BG(BUF)                                                        \
    { float _vv[4] = {nb.x, nb.y, nb.z, nb.w};                               \
      _Pragma("unroll")                                                      \
      for (int _j = 0; _j < 4; ++_j) {                                       \
          int _p = spb + _j;                                                 \
          Bs[BUF][_p * 64 + (((sk >> 3) ^ SWZ(_p)) << 3) + (sk & 7)]         \
              = f2bf(_vv[_j]);                                               \
      } }

#define EMITG(TS, BUF)                                                       \
    if (w < 4) {                                                             \
        s16x8 _ev = *reinterpret_cast<const s16x8*>(&Bs[BUF][tid * 8]);      \
        *reinterpret_cast<s16x8*>(                                           \
            xbfT + ((size_t)(b * 4 + ((TS) >> 3)) * HW_ + p0 + ep) * 512     \
            + ((TS) & 7) * 64 + ec * 8) = _ev;                               \
    }

#define COMPUTEG(BUF)                                                        \
    { _Pragma("unroll")                                                      \
      for (int h = 0; h < 2; ++h) {                                          \
          s16x8 aq = *reinterpret_cast<const s16x8*>(                        \
              &As[BUF][aq_row * 64 + a_sl[h]]);                              \
          s16x8 ak = *reinterpret_cast<const s16x8*>(                        \
              &As[BUF][ak_row * 64 + a_sl[h]]);                              \
          s16x8 b0 = *reinterpret_cast<const s16x8*>(                        \
              &Bs[BUF][li * 64 + b_sl0[h]]);                                 \
          s16x8 b1 = *reinterpret_cast<const s16x8*>(                        \
              &Bs[BUF][(16 + li) * 64 + b_sl1[h]]);                          \
          __builtin_amdgcn_s_setprio(1);                                     \
          accq[0] = MFMA16(aq, b0, accq[0]);                                 \
          accq[1] = MFMA16(aq, b1, accq[1]);                                 \
          acck[0] = MFMA16(ak, b0, acck[0]);                                 \
          acck[1] = MFMA16(ak, b1, acck[1]);                                 \
          __builtin_amdgcn_s_setprio(0);                                     \
      } }

#define PACKG(T)                                                             \
    {   float4 _bqv = *reinterpret_cast<const float4*>(bq + (T) * 128 + ob4);\
        float4 _bkv = *reinterpret_cast<const float4*>(bk + (T) * 128 + ob4);\
        _Pragma("unroll")                                                    \
        for (int _ph = 0; _ph < 2; ++_ph) {                                  \
            Qr[T][_ph * 2 + 0] = pack_bf2(accq[_ph][0] + _bqv.x,             \
                                          accq[_ph][1] + _bqv.y);            \
            Qr[T][_ph * 2 + 1] = pack_bf2(accq[_ph][2] + _bqv.z,             \
                                          accq[_ph][3] + _bqv.w);            \
            Kr[T][_ph * 2 + 0] = pack_bf2(acck[_ph][0] + _bkv.x,             \
                                          acck[_ph][1] + _bkv.y);            \
            Kr[T][_ph * 2 + 1] = pack_bf2(acck[_ph][2] + _bkv.z,             \
                                          acck[_ph][3] + _bkv.w);            \
            accq[_ph] = 0.f;                                                 \
            acck[_ph] = 0.f;                                                 \
        } }

    LOAD_BG(0);
    STAGE_AG(0, 0);
    WRITE_BG(0);
    VMCNT0; LGK0;
    __builtin_amdgcn_s_barrier();

#pragma unroll
    for (int ts = 0; ts < 32; ++ts) {
        if (ts < 31) { LOAD_BG(ts + 1); STAGE_AG(ts + 1, (ts + 1) & 1); }
        EMITG(ts, ts & 1);
        COMPUTEG(ts & 1);
        if (ts == 7)  PACKG(0);
        if (ts == 15) PACKG(1);
        if (ts == 23) PACKG(2);
        if (ts == 31) PACKG(3);
        if (ts < 31) {
            WRITE_BG((ts + 1) & 1);
            VMCNT0; LGK0;
            __builtin_amdgcn_s_barrier();
        }
    }

#undef STAGE_AG
#undef LOAD_BG
#undef WRITE_BG
#undef EMITG
#undef COMPUTEG
#undef PACKG

    float d[24];
#pragma unroll
    for (int t1 = 0; t1 < 4; ++t1)
#pragma unroll
        for (int t2 = 0; t2 < 4; ++t2) {
            float s = 0.f;
#pragma unroll
            for (int j = 0; j < 4; ++j) s += dot2u(Qr[t1][j], Kr[t2][j]);
            d[t1 * 4 + t2] = s;
        }
#pragma unroll
    for (int t = 0; t < 4; ++t) {
        float sq = 0.f, sk2 = 0.f;
#pragma unroll
        for (int j = 0; j < 4; ++j) {
            sq += dot2u(Qr[t][j], Qr[t][j]);
            sk2 += dot2u(Kr[t][j], Kr[t][j]);
        }
        d[16 + t] = sq;
        d[20 + t] = sk2;
    }

    __shared__ float red[8][24];
#pragma unroll
    for (int e = 0; e < 24; ++e) {
        float v = d[e];
#pragma unroll
        for (int o = 32; o > 0; o >>= 1) v += __shfl_down(v, o);
        if (lane == 0) red[w][e] = v;
    }
    __syncthreads();
    if (tid < 24) {
        float t = 0.f;
#pragma unroll
        for (int ww = 0; ww < 8; ++ww) t += red[ww][tid];
        g4[((size_t)b * 24 + tid) * 128 + pblk] = t;
    }
}

// ---------------------------------------------------------------------------
// att_k6: sum 128 gram chunks, cosine energy + softmax -> att (B,S,S)
// ---------------------------------------------------------------------------
__global__ void att_k6(const float* __restrict__ g4, float* __restrict__ att) {
    __shared__ float sm[8][24];
    const int tid = threadIdx.x;
    if (tid < 192) {
        const int b = tid / 24, e = tid % 24;
        const float* p = g4 + ((size_t)b * 24 + e) * 128;
        float t = 0.f;
        for (int ch = 0; ch < 128; ++ch) t += p[ch];
        sm[b][e] = t;
    }
    __syncthreads();
    if (tid < 8) {
        const int b = tid;
        float nq[4], nk[4];
#pragma unroll
        for (int s = 0; s < 4; ++s) {
            nq[s] = sqrtf(sm[b][16 + s]) + EPS_F;
            nk[s] = sqrtf(sm[b][20 + s]) + EPS_F;
        }
#pragma unroll
        for (int s = 0; s < 4; ++s) {
            float e[4], m = -1e30f;
#pragma unroll
            for (int t = 0; t < 4; ++t) {
                e[t] = sm[b][s * 4 + t] / (nq[s] * nk[t]);
                m = fmaxf(m, e[t]);
            }
            float sum = 0.f;
#pragma unroll
            for (int t = 0; t < 4; ++t) { e[t] = expf(e[t] - m); sum += e[t]; }
#pragma unroll
            for (int t = 0; t < 4; ++t)
                att[(size_t)(b * 4 + s) * 4 + t] = e[t] / sum;
        }
    }
}

// ===========================================================================
// vblend12c (r15 champion): fused V-GEMM + 4-s register blend + bias + gamma
// + residual. Correct xbfT base (bt*HW*512); residual re-read in epilogue
// from xbfT (no cross-loop liveness -> no spill); fp32 x read eliminated.
// ===========================================================================
__global__ __launch_bounds__(256, 4) void vblend12c(
    const ushort_t* __restrict__ Wvb_pre, const ushort_t* __restrict__ xbfT,
    const float* __restrict__ bv, const float* __restrict__ att,
    const float* __restrict__ gamma, float* __restrict__ out) {

    // 4096 blocks: xcd = b (8); idx: pblk(64) x cblk(8), cblk innermost
    const int b = blockIdx.x & 7;
    const int idx = blockIdx.x >> 3;
    const int cblk = idx & 7;
    const int p0 = (idx >> 3) * 64;
    const int ct = cblk >> 2;
    const int csub = cblk & 3;

    __shared__ __align__(16) ushort_t AsAll[2 * 4096];   // 16KB
    __shared__ __align__(16) ushort_t BsAll[2 * 4096];   // 16KB

    const int tid = threadIdx.x;
    const int w = tid >> 6, lane = tid & 63;
    const int wr2 = w >> 1, wc2 = w & 1;
    const int li = lane & 15, lk = lane >> 4;

    int a_sl[2], b_sl[2], b_sl1[2];
    const int bp = wc2 * 32 + li;
    const int bp1 = bp + 16;
#pragma unroll
    for (int h = 0; h < 2; ++h) {
        a_sl[h] = (((h * 4 + lk) ^ (li & 7)) << 3);
        b_sl[h] = (((h * 4 + lk) ^ SWZ(bp)) << 3);
        b_sl1[h] = (((h * 4 + lk) ^ SWZ(bp1)) << 3);
    }

    float attv[16];
#pragma unroll
    for (int i = 0; i < 16; ++i)
        attv[i] = __uint_as_float(__builtin_amdgcn_readfirstlane(
            __float_as_uint(att[b * 16 + i])));

    const int bst_p0 = tid >> 3, bst_sl0 = tid & 7;
    const int bst_c0 = bst_sl0 ^ SWZ(bst_p0);
    const int bst_p1 = (tid + 256) >> 3, bst_sl1 = tid & 7;
    const int bst_c1 = bst_sl1 ^ SWZ(bst_p1);

    f32x4 acc[2][2];
    f32x4 mst[4][2][2];
#pragma unroll
    for (int mf = 0; mf < 2; ++mf)
#pragma unroll
        for (int nf = 0; nf < 2; ++nf) acc[mf][nf] = 0.f;
#pragma unroll
    for (int so = 0; so < 4; ++so)
#pragma unroll
        for (int mf = 0; mf < 2; ++mf)
#pragma unroll
            for (int nf = 0; nf < 2; ++nf) mst[so][mf][nf] = 0.f;

#define STAGE12(TS, BUF)                                                     \
    {   const int _t = (TS) >> 3, _kt = (TS) & 7;                            \
        const ushort_t* _ap = Wvb_pre +                                      \
            (((size_t)(_t * 2 + ct) * 8 + _kt) << 14) + (csub << 12);        \
        ushort_t* _al = &AsAll[(BUF) * 4096];                                \
        GLOAD16(_ap + (size_t)(w << 9) + (size_t)(lane << 3),                \
                _al + (w << 9));                                             \
        GLOAD16(_ap + 2048 + (size_t)(w << 9) + (size_t)(lane << 3),         \
                _al + 2048 + (w << 9));                                      \
        const ushort_t* _bb = xbfT + (size_t)(b * 4 + _t) * HW_ * 512;       \
        GLOAD16(_bb + ((size_t)(p0 + bst_p0)) * 512 + _kt * 64 + bst_c0 * 8, \
                &BsAll[(BUF) * 4096 + (w << 9)]);                            \
        GLOAD16(_bb + ((size_t)(p0 + bst_p1)) * 512 + _kt * 64 + bst_c1 * 8, \
                &BsAll[(BUF) * 4096 + 2048 + (w << 9)]);                     \
    }

#define COMPUTE12(BUF)                                                      \
    {   const int _ab = (BUF) * 4096, _bbf = (BUF) * 4096;                  \
        _Pragma("unroll")                                                    \
        for (int h = 0; h < 2; ++h) {                                        \
            s16x8 af0 = *reinterpret_cast<const s16x8*>(                     \
                &AsAll[_ab + (wr2 * 32 + 0 * 16 + li) * 64 + a_sl[h]]);      \
            s16x8 af1 = *reinterpret_cast<const s16x8*>(                     \
                &AsAll[_ab + (wr2 * 32 + 1 * 16 + li) * 64 + a_sl[h]]);      \
            s16x8 bf0 = *reinterpret_cast<const s16x8*>(                     \
                &BsAll[_bbf + bp * 64 + b_sl[h]]);                           \
            s16x8 bf1 = *reinterpret_cast<const s16x8*>(                     \
                &BsAll[_bbf + bp1 * 64 + b_sl1[h]]);                         \
            __builtin_amdgcn_s_setprio(1);                                   \
            acc[0][0] = MFMA16(af0, bf0, acc[0][0]);                         \
            acc[0][1] = MFMA16(af0, bf1, acc[0][1]);                         \
            acc[1][0] = MFMA16(af1, bf0, acc[1][0]);                         \
            acc[1][1] = MFMA16(af1, bf1, acc[1][1]);                         \
            __builtin_amdgcn_s_setprio(0);                                   \
        } }

#define BLEND12(T2)                                                          \
    { _Pragma("unroll")                                                      \
      for (int _so = 0; _so < 4; ++_so)                                      \
          _Pragma("unroll")                                                  \
          for (int _mf = 0; _mf < 2; ++_mf)                                  \
              _Pragma("unroll")                                              \
              for (int _nf = 0; _nf < 2; ++_nf)                              \
                  mst[_so][_mf][_nf] += attv[_so * 4 + (T2)] * acc[_mf][_nf];\
      _Pragma("unroll")                                                      \
      for (int _mf = 0; _mf < 2; ++_mf)                                      \
          _Pragma("unroll")                                                  \
          for (int _nf = 0; _nf < 2; ++_nf) acc[_mf][_nf] = 0.f; }

    STAGE12(0, 0);
    VMCNT0;
    __builtin_amdgcn_s_barrier();

#pragma unroll
    for (int ts = 0; ts < 32; ++ts) {
        if (ts < 31) STAGE12(ts + 1, (ts + 1) & 1);
        COMPUTE12(ts & 1);
        if (ts == 7)  BLEND12(0);
        if (ts == 15) BLEND12(1);
        if (ts == 23) BLEND12(2);
        if (ts == 31) BLEND12(3);
        if (ts < 31) {
            VMCNT0;
            __builtin_amdgcn_s_barrier();
        }
    }

#undef STAGE12
#undef COMPUTE12
#undef BLEND12

    // epilogue: out = gm*(mst + bsum) + bf16_residual (re-read from xbfT).
    const float gm = gamma[0];
    const int c0 = cblk * 64;
    const int cbase = c0 + wr2 * 32 + lk * 4;

    float bsv[2][4][4];   // [mf][r][so]
#pragma unroll
    for (int mf = 0; mf < 2; ++mf)
#pragma unroll
        for (int r = 0; r < 4; ++r) {
            int c = cbase + mf * 16 + r;
            float b0 = bv[0 * 512 + c], b1 = bv[1 * 512 + c];
            float b2 = bv[2 * 512 + c], b3 = bv[3 * 512 + c];
#pragma unroll
            for (int so = 0; so < 4; ++so)
                bsv[mf][r][so] = attv[so * 4 + 0] * b0 + attv[so * 4 + 1] * b1
                               + attv[so * 4 + 2] * b2 + attv[so * 4 + 3] * b3;
        }

#pragma unroll
    for (int so = 0; so < 4; ++so) {
#pragma unroll
        for (int nf = 0; nf < 2; ++nf) {
            const int p = p0 + wc2 * 32 + nf * 16 + li;
            const ushort_t* rb =
                xbfT + ((size_t)(b * 4 + so) * HW_ + p) * 512 + cbase;
            const uint2 vA = *reinterpret_cast<const uint2*>(rb);       // mf=0
            const uint2 vB = *reinterpret_cast<const uint2*>(rb + 16);  // mf=1
#pragma unroll
            for (int mf = 0; mf < 2; ++mf) {
                const uint2 v = mf ? vB : vA;
#pragma unroll
                for (int r = 0; r < 4; ++r) {
                    float resid = (r == 0) ? bf_lo(v.x)
                                : (r == 1) ? bf_hi(v.x)
                                : (r == 2) ? bf_lo(v.y)
                                           : bf_hi(v.y);
                    int c = cbase + mf * 16 + r;
                    size_t off = ((size_t)(b * 4 + so) * C_ + c) * HW_ + p;
                    out[off] = gm * (mst[so][mf][nf][r] + bsv[mf][r][so]) + resid;
                }
            }
        }
    }
}

extern "C" void kernel_launch(void* const* d_in, const int* in_sizes, int n_in,
                              void* d_out, int out_size, void* d_ws, size_t ws_size,
                              hipStream_t stream) {
    const float* x     = (const float*)d_in[0];
    const float* wq    = (const float*)d_in[1];
    const float* bq    = (const float*)d_in[2];
    const float* wk    = (const float*)d_in[3];
    const float* bk    = (const float*)d_in[4];
    const float* wv    = (const float*)d_in[5];
    const float* bv    = (const float*)d_in[6];
    const float* gamma = (const float*)d_in[7];
    float* out = (float*)d_out;

    char* ws = (char*)d_ws;
    ushort_t* Wqk_pre = (ushort_t*)ws;                          // 1.05 MB
    ushort_t* Wvb_pre = Wqk_pre + (size_t)4 * 8 * 256 * 64;     // 4.19 MB
    float*    g4      = (float*)(Wvb_pre + (size_t)4 * 2 * 8 * 256 * 64);  // 98 KB
    float*    att     = g4 + (size_t)8 * 24 * 128;
    ushort_t* xbfT    = (ushort_t*)(att + 128);                 // 134.2 MB

    prep3<<<768, 256, 0, stream>>>(wq, wk, wv, Wqk_pre, Wvb_pre);
    qkg<<<1024, 512, 0, stream>>>(Wqk_pre, x, bq, bk, xbfT, g4);
    att_k6<<<1, 256, 0, stream>>>(g4, att);
    vblend12c<<<4096, 256, 0, stream>>>(Wvb_pre, xbfT, bv, att, gamma, out);
}